// Round 2
// 785.878 us; speedup vs baseline: 1.0941x; 1.0941x over previous
//
#include <hip/hip_runtime.h>
#include <stdint.h>

// ---------- types ----------
typedef unsigned short ushort_t;
typedef __attribute__((ext_vector_type(4))) float  floatx4;
typedef __attribute__((ext_vector_type(8))) short  shortx8;   // 8 bf16 (4 VGPRs)

// ---------- bf16 helpers (raw ushort representation) ----------
__device__ __forceinline__ float bf2f(ushort_t u) {
  union { float f; unsigned int i; } x; x.i = ((unsigned int)u) << 16; return x.f;
}
__device__ __forceinline__ ushort_t f2bf(float f) {
  union { float f; unsigned int i; } x; x.f = f;
  unsigned int r = x.i + 0x7fffu + ((x.i >> 16) & 1u);   // RNE
  return (ushort_t)(r >> 16);
}

// ---------- async global->LDS, 16B per lane ----------
__device__ __forceinline__ void gl_lds16(const ushort_t* g, ushort_t* l) {
  __builtin_amdgcn_global_load_lds(
      (const __attribute__((address_space(1))) void*)g,
      (__attribute__((address_space(3))) void*)l, 16, 0, 0);
}

#define BARRIER() __builtin_amdgcn_s_barrier()
#define SCHED0()  __builtin_amdgcn_sched_barrier(0)

// ---------- fp32 -> bf16 cast, 8 elems/thread ----------
__global__ __launch_bounds__(256) void cast_f32_bf16(const float* __restrict__ in,
                                                     ushort_t* __restrict__ out, long n) {
  long i = ((long)blockIdx.x * 256 + threadIdx.x) * 8;
  if (i + 8 > n) return;
  floatx4 a = *(const floatx4*)(in + i);
  floatx4 b = *(const floatx4*)(in + i + 4);
  union { shortx8 v; ushort_t h[8]; } u;
  u.h[0] = f2bf(a.x); u.h[1] = f2bf(a.y); u.h[2] = f2bf(a.z); u.h[3] = f2bf(a.w);
  u.h[4] = f2bf(b.x); u.h[5] = f2bf(b.y); u.h[6] = f2bf(b.z); u.h[7] = f2bf(b.w);
  *(shortx8*)(out + i) = u.v;
}

// ---------- 256x256-tile 8-phase GEMM: C[M][1024] = A[M][1024] * B^T + bias ----------
// A: bf16 [M][K=1024] row-major; B: bf16 [1024][1024] row-major (weights).
// OMODE: 0 = bf16 out, 1 = bf16 out + per-head-row L2 norm * gamma (q-norm fused),
//        2 = fp32 out. PBB: B has a per-batch slab of 1M elems selected by tile row.
// grid 512 (1-D, XCD-swizzled to (tx,ty) = (128,4)), block 512 (8 waves, 2m x 4n).
// Schedule: T3+T4 counted-vmcnt phases, T2 XOR swizzle, T5 setprio, T1 XCD swizzle.
// Phase order {A0B0->q00}{B1->q01}{A1->q11}{->q10} keeps only one A-chunk set live
// at a time (peak fragment liveness 64 VGPR vs 80 for the naive order).
#define MFMA_QUAD(AH, BH, MH, NH)                                              \
  SCHED0();                                                                    \
  __builtin_amdgcn_s_setprio(1);                                               \
  _Pragma("unroll") for (int i_ = 0; i_ < 4; ++i_)                             \
  _Pragma("unroll") for (int j_ = 0; j_ < 2; ++j_)                             \
  _Pragma("unroll") for (int s_ = 0; s_ < 2; ++s_)                             \
    acc[(MH)*4 + i_][(NH)*2 + j_] = __builtin_amdgcn_mfma_f32_16x16x32_bf16(   \
        AH[i_][s_], BH[j_][s_], acc[(MH)*4 + i_][(NH)*2 + j_], 0, 0, 0);       \
  __builtin_amdgcn_s_setprio(0);                                               \
  SCHED0();

template <int OMODE, bool PBB>
__global__ __launch_bounds__(512, 2) void gemm_bt(const ushort_t* __restrict__ A,
                                                  const ushort_t* __restrict__ B,
                                                  const float* __restrict__ bias,
                                                  const float* __restrict__ gamma,
                                                  void* __restrict__ Cv) {
  constexpr int K  = 1024;
  constexpr int N  = 1024;
  constexpr int NT = K / 64;          // 16 K-tiles

  // [slot][chunk][128 rows][64 cols] bf16, 16 KiB per chunk; 128 KiB total
  __shared__ ushort_t Abuf[2][2][8192];
  __shared__ ushort_t Bbuf[2][2][8192];

  const int t    = threadIdx.x;
  const int lane = t & 63;
  const int w    = t >> 6;            // 0..7
  const int wm   = w >> 2;            // 0..1
  const int wn   = w & 3;             // 0..3

  // T1: bijective XCD swizzle (512 blocks, 8 XCDs, 64/XCD; y-fastest decode
  // so the 4 N-blocks sharing an A panel are consecutive on one XCD)
  const int bid  = blockIdx.x;
  const int perm = ((bid & 7) << 6) | (bid >> 3);
  const int tx   = perm >> 2;         // 0..127  (M tiles)
  const int ty   = perm & 3;          // 0..3    (N tiles)
  const size_t row0 = (size_t)tx * 256;
  const int    col0 = ty * 256;
  const size_t boff = PBB ? ((size_t)(tx >> 5)) * (size_t)(1024 * 1024) : 0;

  // ---- staging: linear LDS dest + inverse-swizzled global source ----
  // chunk = 128 rows x 64 cols; 2 rounds of 512 thr x 16B; 16B-slot ^= (row&7)
  const int tr  = t >> 3;                  // row within round (0..63)
  const int swz = (t & 7) ^ (tr & 7);      // swizzled 16B-slot within 128B row
  const ushort_t* Asrc0 = A + (row0 + tr) * K + swz * 8;
  const ushort_t* Bsrc0 = B + boff + ((size_t)col0 + (size_t)(tr >> 5) * 64 + (tr & 31)) * K + swz * 8;

  auto stageA = [&](int T, int mh) {      // A-chunk mh: rows {mh*64..+63, mh*64+128..+191}
    ushort_t* dst = &Abuf[T & 1][mh][0] + t * 8;
    const ushort_t* s0 = Asrc0 + (size_t)mh * 64 * K + T * 64;
    gl_lds16(s0, dst);                    // round 0: LDS rows  0..63 of chunk
    gl_lds16(s0 + 128 * K, dst + 4096);   // round 1: LDS rows 64..127
  };
  auto stageB = [&](int T, int nh) {      // B-chunk nh: rows nh*32 + {0..31,64..95,128..159,192..223}
    ushort_t* dst = &Bbuf[T & 1][nh][0] + t * 8;
    const ushort_t* s0 = Bsrc0 + (size_t)nh * 32 * K + T * 64;
    gl_lds16(s0, dst);
    gl_lds16(s0 + 128 * K, dst + 4096);
  };

  // ---- ds_read addressing (swizzled): conflict-free b128 ----
  const int fr = lane & 15;
  const int g4 = lane >> 4;
  const int q  = fr & 7;
  int aRd[2], bRd[2];
#pragma unroll
  for (int s = 0; s < 2; ++s) {
    aRd[s] = (wm * 64 + fr) * 128 + (((4 * s + g4) ^ q) * 16);
    bRd[s] = (wn * 32 + fr) * 128 + (((4 * s + g4) ^ q) * 16);
  }
  const char* AbufB = (const char*)&Abuf[0][0][0];
  const char* BbufB = (const char*)&Bbuf[0][0][0];

  shortx8 a0[4][2], a1[4][2], b0[2][2], b1[2][2];
  floatx4 acc[8][4] = {};

  auto ldA = [&](shortx8 (&d)[4][2], int slot, int mh) {   // 8x ds_read_b128
    const char* base = AbufB + slot * 32768 + mh * 16384;
#pragma unroll
    for (int i = 0; i < 4; ++i)
#pragma unroll
      for (int s = 0; s < 2; ++s)
        d[i][s] = *(const shortx8*)(base + i * 2048 + aRd[s]);
  };
  auto ldB = [&](shortx8 (&d)[2][2], int slot, int nh) {   // 4x ds_read_b128
    const char* base = BbufB + slot * 32768 + nh * 16384;
#pragma unroll
    for (int j = 0; j < 2; ++j)
#pragma unroll
      for (int s = 0; s < 2; ++s)
        d[j][s] = *(const shortx8*)(base + j * 2048 + bRd[s]);
  };

  // ---- prologue: tile0 {A0,B0,A1,B1} + tile1 {A0,B0,A1}; vmcnt(6) -> tile0 landed
  stageA(0, 0); stageB(0, 0); stageA(0, 1); stageB(0, 1);
  stageA(1, 0); stageB(1, 0); stageA(1, 1);
  asm volatile("s_waitcnt vmcnt(6)" ::: "memory");
  SCHED0();
  BARRIER();

  // ---- main loop: 4 phases per K-tile (2 barriers each).
  // Stage plan per tile T: p0:(T+1).B1  p1:(T+2).A0  p2:(T+2).B0  p3:(T+2).A1
  //   (each lands >=1 barrier after the destination chunk's last ds_read drained).
  // End-of-tile vmcnt(6): retires exactly tile T+1's 8 loads, leaves (T+2).{A0,B0,A1}.
#pragma unroll 2
  for (int T = 0; T < NT; ++T) {
    const int slot = T & 1;
    // phase 0: read A0+B0 (12 ds_reads); stage (T+1).B1; MFMA q(0,0)
    ldA(a0, slot, 0);
    ldB(b0, slot, 0);
    if (T + 1 < NT) stageB(T + 1, 1);
    BARRIER();
    asm volatile("s_waitcnt lgkmcnt(0)" ::: "memory");
    MFMA_QUAD(a0, b0, 0, 0);
    BARRIER();
    // phase 1: read B1; stage (T+2).A0; MFMA q(0,1)  [a0 dies here]
    ldB(b1, slot, 1);
    if (T + 2 < NT) stageA(T + 2, 0);
    BARRIER();
    asm volatile("s_waitcnt lgkmcnt(0)" ::: "memory");
    MFMA_QUAD(a0, b1, 0, 1);
    BARRIER();
    // phase 2: read A1; stage (T+2).B0; MFMA q(1,1)  [b1 dies here]
    ldA(a1, slot, 1);
    if (T + 2 < NT) stageB(T + 2, 0);
    BARRIER();
    asm volatile("s_waitcnt lgkmcnt(0)" ::: "memory");
    MFMA_QUAD(a1, b1, 1, 1);
    BARRIER();
    // phase 3: stage (T+2).A1; MFMA q(1,0) (a1,b0 already in regs); counted vmcnt
    if (T + 2 < NT) stageA(T + 2, 1);
    BARRIER();
    MFMA_QUAD(a1, b0, 1, 0);
    if (T + 2 < NT)      { asm volatile("s_waitcnt vmcnt(6)" ::: "memory"); }
    else if (T + 1 < NT) { asm volatile("s_waitcnt vmcnt(0)" ::: "memory"); }
    SCHED0();
    BARRIER();
  }

  // ---- epilogue ----
  // C/D layout: row = (lane>>4)*4 + reg, col = lane&15  [verified]
  const int cr = g4 * 4;
  const int cc = fr;

  float bcol[4];
#pragma unroll
  for (int j2 = 0; j2 < 4; ++j2) bcol[j2] = bias[col0 + wn * 64 + j2 * 16 + cc];
#pragma unroll
  for (int mt = 0; mt < 8; ++mt)
#pragma unroll
    for (int j2 = 0; j2 < 4; ++j2)
#pragma unroll
      for (int i = 0; i < 4; ++i) acc[mt][j2][i] += bcol[j2];

  if (OMODE == 1) {
    // this wave's 64-col strip == one head; row-L2 normalize * gamma[h]
    const float gm = gamma[ty * 4 + wn];
#pragma unroll
    for (int mt = 0; mt < 8; ++mt) {
#pragma unroll
      for (int i = 0; i < 4; ++i) {
        float ss = 0.f;
#pragma unroll
        for (int j2 = 0; j2 < 4; ++j2) { float v = acc[mt][j2][i]; ss += v * v; }
        ss += __shfl_xor(ss, 1);
        ss += __shfl_xor(ss, 2);
        ss += __shfl_xor(ss, 4);
        ss += __shfl_xor(ss, 8);
        const float sc = gm * rsqrtf(ss);
#pragma unroll
        for (int j2 = 0; j2 < 4; ++j2) acc[mt][j2][i] *= sc;
      }
    }
  }

#pragma unroll
  for (int mt = 0; mt < 8; ++mt) {
    size_t r0 = row0 + wm * 128 + mt * 16 + cr;
#pragma unroll
    for (int j2 = 0; j2 < 4; ++j2) {
      int col = col0 + wn * 64 + j2 * 16 + cc;
#pragma unroll
      for (int i = 0; i < 4; ++i) {
        float v = acc[mt][j2][i];
        size_t idx = (r0 + i) * N + col;
        if (OMODE == 2) ((float*)Cv)[idx]    = v;
        else            ((ushort_t*)Cv)[idx] = f2bf(v);
      }
    }
  }
}

// ---------- kv split-K partials: kvpart[bh][s][64][64] = sum over 256 n ----------
// K,V: bf16 [4*8192][1024]. grid (64, 32) = (b*16+h, s), block 256.
__global__ __launch_bounds__(256) void kv_partial(const ushort_t* __restrict__ Kp,
                                                  const ushort_t* __restrict__ Vp,
                                                  float* __restrict__ kvpart) {
  const int bh = blockIdx.x;
  const int h  = bh & 15;
  const long boff = (long)(bh >> 4) * 8192 * 1024;
  const int s = blockIdx.y;
  const int t = threadIdx.x;
  __shared__ float Kl[64 * 64];
  __shared__ float Vl[64 * 64];

  const int d0 = (t >> 4) * 4;
  const int e0 = (t & 15) * 4;
  float acc[4][4] = {};

  for (int c = 0; c < 4; ++c) {
    const int n0 = s * 256 + c * 64;
    __syncthreads();
#pragma unroll
    for (int r = 0; r < 2; ++r) {
      int row = (t >> 3) + 32 * r;
      int seg = (t & 7) * 8;
      union { shortx8 v; ushort_t hh[8]; } uk, uv;
      uk.v = *(const shortx8*)(Kp + boff + (size_t)(n0 + row) * 1024 + h * 64 + seg);
      uv.v = *(const shortx8*)(Vp + boff + (size_t)(n0 + row) * 1024 + h * 64 + seg);
      floatx4 k03 = { bf2f(uk.hh[0]), bf2f(uk.hh[1]), bf2f(uk.hh[2]), bf2f(uk.hh[3]) };
      floatx4 k47 = { bf2f(uk.hh[4]), bf2f(uk.hh[5]), bf2f(uk.hh[6]), bf2f(uk.hh[7]) };
      floatx4 v03 = { bf2f(uv.hh[0]), bf2f(uv.hh[1]), bf2f(uv.hh[2]), bf2f(uv.hh[3]) };
      floatx4 v47 = { bf2f(uv.hh[4]), bf2f(uv.hh[5]), bf2f(uv.hh[6]), bf2f(uv.hh[7]) };
      *(floatx4*)&Kl[row * 64 + seg]     = k03;
      *(floatx4*)&Kl[row * 64 + seg + 4] = k47;
      *(floatx4*)&Vl[row * 64 + seg]     = v03;
      *(floatx4*)&Vl[row * 64 + seg + 4] = v47;
    }
    __syncthreads();
#pragma unroll 8
    for (int nn = 0; nn < 64; ++nn) {
      floatx4 kk = *(const floatx4*)&Kl[nn * 64 + d0];
      floatx4 vv = *(const floatx4*)&Vl[nn * 64 + e0];
#pragma unroll
      for (int i = 0; i < 4; ++i)
#pragma unroll
        for (int j = 0; j < 4; ++j)
          acc[i][j] += kk[i] * vv[j];
    }
  }
  float* dst = kvpart + ((size_t)bh * 32 + s) * 4096;
#pragma unroll
  for (int i = 0; i < 4; ++i) {
    floatx4 row = { acc[i][0], acc[i][1], acc[i][2], acc[i][3] };
    *(floatx4*)&dst[(d0 + i) * 64 + e0] = row;
  }
}

// ---------- reduce partials + row-L2-normalize * gamma -> kvn[bh][64][64] fp32 ----------
__global__ __launch_bounds__(256) void kv_norm(const float* __restrict__ kvpart,
                                               const float* __restrict__ gamma,
                                               float* __restrict__ kvn) {
  const int bh = blockIdx.x;
  const int t = threadIdx.x;
  const int d  = t >> 2;
  const int e0 = (t & 3) * 16;
  floatx4 v[4] = {};
  for (int s = 0; s < 32; ++s) {
    const float* p = kvpart + ((size_t)bh * 32 + s) * 4096 + d * 64 + e0;
#pragma unroll
    for (int q = 0; q < 4; ++q) v[q] += *(const floatx4*)(p + q * 4);
  }
  float ss = 0.f;
#pragma unroll
  for (int q = 0; q < 4; ++q)
    ss += v[q].x * v[q].x + v[q].y * v[q].y + v[q].z * v[q].z + v[q].w * v[q].w;
  ss += __shfl_xor(ss, 1, 64);
  ss += __shfl_xor(ss, 2, 64);
  float sc = gamma[bh & 15] * rsqrtf(ss);
  float* dst = kvn + (size_t)bh * 4096 + d * 64 + e0;
#pragma unroll
  for (int q = 0; q < 4; ++q) { floatx4 o = v[q] * sc; *(floatx4*)(dst + q * 4) = o; }
}

// ---------- W2T[b][o][h*64+d] = sum_e kvn[bh][d][e] * Wo[o][h*64+e], bf16 out ----------
// grid (64 bh, 16 o-tiles), block 256
__global__ __launch_bounds__(256) void w2_kernel(const float* __restrict__ kvn,
                                                 const float* __restrict__ Wo,
                                                 ushort_t* __restrict__ W2T) {
  const int bh = blockIdx.x;
  const int h  = bh & 15;
  const int ot = blockIdx.y;
  const int t  = threadIdx.x;
  __shared__ float kvt[64 * 64];   // [e][d]
  __shared__ float wot[64 * 64];   // [e][o]
#pragma unroll
  for (int p = 0; p < 4; ++p) {
    int r  = p * 16 + (t >> 4);
    int c4 = (t & 15) * 4;
    floatx4 a = *(const floatx4*)&kvn[(size_t)bh * 4096 + r * 64 + c4];
    floatx4 b = *(const floatx4*)&Wo[(size_t)(ot * 64 + r) * 1024 + h * 64 + c4];
    kvt[(c4 + 0) * 64 + r] = a.x; kvt[(c4 + 1) * 64 + r] = a.y;
    kvt[(c4 + 2) * 64 + r] = a.z; kvt[(c4 + 3) * 64 + r] = a.w;
    wot[(c4 + 0) * 64 + r] = b.x; wot[(c4 + 1) * 64 + r] = b.y;
    wot[(c4 + 2) * 64 + r] = b.z; wot[(c4 + 3) * 64 + r] = b.w;
  }
  __syncthreads();
  const int d0 = (t >> 4) * 4;
  const int o0 = (t & 15) * 4;
  float acc[4][4] = {};
#pragma unroll 8
  for (int e = 0; e < 64; ++e) {
    floatx4 kk = *(const floatx4*)&kvt[e * 64 + d0];
    floatx4 ww = *(const floatx4*)&wot[e * 64 + o0];
#pragma unroll
    for (int i = 0; i < 4; ++i)
#pragma unroll
      for (int j = 0; j < 4; ++j)
        acc[i][j] += kk[i] * ww[j];
  }
  ushort_t* dst = W2T + (size_t)(bh >> 4) * 1024 * 1024;
#pragma unroll
  for (int j = 0; j < 4; ++j)
#pragma unroll
    for (int i = 0; i < 4; ++i)
      dst[(size_t)(ot * 64 + o0 + j) * 1024 + h * 64 + d0 + i] = f2bf(acc[i][j]);
}

// ---------- host orchestration ----------
extern "C" void kernel_launch(void* const* d_in, const int* in_sizes, int n_in,
                              void* d_out, int out_size, void* d_ws, size_t ws_size,
                              hipStream_t stream) {
  const float* Xq = (const float*)d_in[0];
  const float* Xk = (const float*)d_in[1];
  const float* Xv = (const float*)d_in[2];
  const float* Wq = (const float*)d_in[3];
  const float* bq = (const float*)d_in[4];
  const float* Wk = (const float*)d_in[5];
  const float* bk = (const float*)d_in[6];
  const float* Wv = (const float*)d_in[7];
  const float* bv = (const float*)d_in[8];
  const float* Wo = (const float*)d_in[9];
  const float* bo = (const float*)d_in[10];
  const float* gamma = (const float*)d_in[11];
  float* out = (float*)d_out;

  const long M  = 4L * 8192;        // all batches stacked
  const long NE = M * 1024;         // total elements across batches

  char* ws = (char*)d_ws;
  auto alloc = [&](size_t bytes) { char* p = ws; ws += (bytes + 255) & ~255ull; return p; };
  ushort_t* XBF = (ushort_t*)alloc(NE * 2);          // reusable X bf16
  ushort_t* QBF = (ushort_t*)alloc(NE * 2);
  ushort_t* KBF = (ushort_t*)alloc(NE * 2);
  ushort_t* VBF = (ushort_t*)alloc(NE * 2);
  ushort_t* WQB = (ushort_t*)alloc(1024 * 1024 * 2);
  ushort_t* WKB = (ushort_t*)alloc(1024 * 1024 * 2);
  ushort_t* WVB = (ushort_t*)alloc(1024 * 1024 * 2);
  float*    KVP = (float*)alloc((size_t)64 * 32 * 4096 * 4);
  float*    KVN = (float*)alloc((size_t)64 * 4096 * 4);
  ushort_t* W2T = (ushort_t*)alloc((size_t)4 * 1024 * 1024 * 2);

  // weights -> bf16
  cast_f32_bf16<<<512, 256, 0, stream>>>(Wq, WQB, 1024 * 1024);
  cast_f32_bf16<<<512, 256, 0, stream>>>(Wk, WKB, 1024 * 1024);
  cast_f32_bf16<<<512, 256, 0, stream>>>(Wv, WVB, 1024 * 1024);

  const int ggrid = 512;   // (M/256=128) x (N/256=4), XCD-swizzled in-kernel

  // Q projection + fused q-norm (all batches)
  cast_f32_bf16<<<16384, 256, 0, stream>>>(Xq, XBF, NE);
  gemm_bt<1, false><<<ggrid, 512, 0, stream>>>(XBF, WQB, bq, gamma, QBF);
  // K projection
  cast_f32_bf16<<<16384, 256, 0, stream>>>(Xk, XBF, NE);
  gemm_bt<0, false><<<ggrid, 512, 0, stream>>>(XBF, WKB, bk, nullptr, KBF);
  // V projection
  cast_f32_bf16<<<16384, 256, 0, stream>>>(Xv, XBF, NE);
  gemm_bt<0, false><<<ggrid, 512, 0, stream>>>(XBF, WVB, bv, nullptr, VBF);

  // kv = K^T V per (b,h), split-K partials + normalize
  kv_partial<<<dim3(64, 32), 256, 0, stream>>>(KBF, VBF, KVP);
  kv_norm<<<64, 256, 0, stream>>>(KVP, gamma, KVN);

  // W2T[b] = kvn[b] folded into Wo
  w2_kernel<<<dim3(64, 16), 256, 0, stream>>>(KVN, Wo, W2T);

  // final = q_n @ W2T[b]^T + bo  (fp32 out, per-batch B slab)
  gemm_bt<2, true><<<ggrid, 512, 0, stream>>>(QBF, W2T, bo, nullptr, out);
}